// Round 1
// baseline (936.394 us; speedup 1.0000x reference)
//
#include <hip/hip_runtime.h>
#include <math.h>

namespace {

constexpr int N = 10000;
constexpr int K = 16;
constexpr int JT = 1024;                 // j-chunk staged in LDS (64 KB)
constexpr int ROWS_PER_BLOCK = 32;       // 8 waves x 4 rows/lane
constexpr int TILES = (N + ROWS_PER_BLOCK - 1) / ROWS_PER_BLOCK;  // 313

// ws layout (floats): [0]=sum(adj)  [1]=tot_struct_unnorm  [2]=tot_att_unnorm
//                     [4..20)=cluster_size[16]
// d_out layout: [0]=clu_loss  [1..1+N)= -struct  [1+N..1+2N)= -att  [1+2N..1+3N)= -(s+a)
// Main kernel writes UNNORMALIZED struct/att into d_out sections 1,2; finalize normalizes.

__global__ __launch_bounds__(512, 4)
void scl_main(const float* __restrict__ adj, const float* __restrict__ att,
              const float* __restrict__ outm, float* __restrict__ ws,
              float* __restrict__ d_out) {
  // output chunk, transposed into 16 per-k planes: planes[k][j_local].
  // Read pattern: lane reads planes[k][jl..jl+3] as float4 -> contiguous
  // 16 B/lane ds_read_b128, conflict-free.
  __shared__ float planes[K][JT];

  const int bx = blockIdx.x;
  const int m = (bx >= TILES) ? 1 : 0;           // 0 = adj, 1 = att
  const int tile = bx - m * TILES;
  const float* __restrict__ A = m ? att : adj;
  const int wave = threadIdx.x >> 6;
  const int lane = threadIdx.x & 63;
  const int r0 = tile * ROWS_PER_BLOCK + wave * 4;
  const bool wv = (r0 + 4) <= N;                 // whole wave valid or not (N%4==0)

  float acc0[K], acc1[K], acc2[K], acc3[K];
#pragma unroll
  for (int k = 0; k < K; ++k) { acc0[k] = 0.f; acc1[k] = 0.f; acc2[k] = 0.f; acc3[k] = 0.f; }
  float rsum = 0.f;
  const float* Ar = A + (size_t)r0 * N;

  for (int c = 0; c < (N + JT - 1) / JT; ++c) {
    const int jbase = c * JT;
    const int clen = (N - jbase) < JT ? (N - jbase) : JT;   // multiple of 4

    // Stage out[jbase .. jbase+clen) -> planes, transposed. Coalesced float4
    // global reads (L2-hot after first touch); 4 ds_write_b32 each (4-way
    // write conflict, negligible volume vs reads).
    for (int idx = threadIdx.x; idx < (clen << 2); idx += 512) {
      const int jj = idx >> 2;
      const int q = idx & 3;
      const float4 v = *(const float4*)(outm + ((size_t)(jbase + jj) << 4) + (q << 2));
      planes[q * 4 + 0][jj] = v.x;
      planes[q * 4 + 1][jj] = v.y;
      planes[q * 4 + 2][jj] = v.z;
      planes[q * 4 + 3][jj] = v.w;
    }
    __syncthreads();

    if (wv) {
      for (int it = 0; it < 4; ++it) {
        const int jl = (it << 8) + (lane << 2);
        if (jl < clen) {
          const float* p = Ar + jbase + jl;
          const float4 a0 = *(const float4*)(p);
          const float4 a1 = *(const float4*)(p + N);
          const float4 a2 = *(const float4*)(p + 2 * N);
          const float4 a3 = *(const float4*)(p + 3 * N);
          rsum += (a0.x + a0.y + a0.z + a0.w) + (a1.x + a1.y + a1.z + a1.w) +
                  (a2.x + a2.y + a2.z + a2.w) + (a3.x + a3.y + a3.z + a3.w);
#pragma unroll
          for (int k = 0; k < K; ++k) {
            const float4 o = *(const float4*)&planes[k][jl];
            acc0[k] += a0.x * o.x + a0.y * o.y + a0.z * o.z + a0.w * o.w;
            acc1[k] += a1.x * o.x + a1.y * o.y + a1.z * o.z + a1.w * o.w;
            acc2[k] += a2.x * o.x + a2.y * o.y + a2.z * o.z + a2.w * o.w;
            acc3[k] += a3.x * o.x + a3.y * o.y + a3.z * o.z + a3.w * o.w;
          }
        }
      }
    }
    __syncthreads();
  }

  // Epilogue: struct_unnorm[i] = sum_k out[i,k] * (sum over lanes of acc[k])
  //         = sum over lanes of (sum_k out[i,k]*acc[k])  -> dot first, then reduce.
  float p0 = 0.f, p1 = 0.f, p2 = 0.f, p3 = 0.f;
  if (wv) {
    const float* o0 = outm + (size_t)r0 * K;
#pragma unroll
    for (int k = 0; k < K; ++k) {
      p0 += o0[k] * acc0[k];
      p1 += o0[K + k] * acc1[k];
      p2 += o0[2 * K + k] * acc2[k];
      p3 += o0[3 * K + k] * acc3[k];
    }
  }
#pragma unroll
  for (int off = 32; off >= 1; off >>= 1) {
    p0 += __shfl_xor(p0, off, 64);
    p1 += __shfl_xor(p1, off, 64);
    p2 += __shfl_xor(p2, off, 64);
    p3 += __shfl_xor(p3, off, 64);
    rsum += __shfl_xor(rsum, off, 64);
  }
  if (lane == 0 && wv) {
    float* dst = d_out + 1 + m * N + r0;
    dst[0] = p0; dst[1] = p1; dst[2] = p2; dst[3] = p3;
    atomicAdd(&ws[1 + m], p0 + p1 + p2 + p3);
    if (m == 0) atomicAdd(&ws[0], rsum);
  }
}

// cluster_size[k] = sum_i out[i,k]. Thread t: k = t&15, row group g = t>>4.
__global__ void scl_colsum(const float* __restrict__ outm, float* __restrict__ ws) {
  __shared__ float red[16][17];
  const int k = threadIdx.x & 15;
  const int g = threadIdx.x >> 4;  // 0..15
  float acc = 0.f;
  for (int r = blockIdx.x * 16 + g; r < N; r += gridDim.x * 16)
    acc += outm[(size_t)r * K + k];
  red[g][k] = acc;
  __syncthreads();
  if (threadIdx.x < 16) {
    float s = 0.f;
#pragma unroll
    for (int gg = 0; gg < 16; ++gg) s += red[gg][threadIdx.x];
    atomicAdd(&ws[4 + threadIdx.x], s);
  }
}

__global__ void scl_finalize(float* __restrict__ d_out, const float* __restrict__ ws) {
  const float S = ws[0];
  const float inv = 1.0f / S;
  const int i = blockIdx.x * blockDim.x + threadIdx.x;
  if (i < N) {
    const float su = d_out[1 + i];
    const float au = d_out[1 + N + i];
    d_out[1 + i] = -su * inv;
    d_out[1 + N + i] = -au * inv;
    d_out[1 + 2 * N + i] = -(su + au) * inv;
  }
  if (blockIdx.x == 0 && threadIdx.x == 0) {
    float cs2 = 0.f;
#pragma unroll
    for (int k = 0; k < K; ++k) cs2 += ws[4 + k] * ws[4 + k];
    const float reg = sqrtf(cs2) / (float)N * 4.0f - 1.0f;  // sqrt(K)=4
    d_out[0] = -((ws[1] + ws[2]) * inv - reg);
  }
}

}  // namespace

extern "C" void kernel_launch(void* const* d_in, const int* in_sizes, int n_in,
                              void* d_out, int out_size, void* d_ws, size_t ws_size,
                              hipStream_t stream) {
  const float* adj  = (const float*)d_in[0];
  const float* att  = (const float*)d_in[1];
  const float* outm = (const float*)d_in[2];
  float* out = (float*)d_out;
  float* ws = (float*)d_ws;

  // Zero the 32-float scalar workspace (harness poisons it with 0xAA).
  hipMemsetAsync(d_ws, 0, 32 * sizeof(float), stream);
  scl_colsum<<<32, 256, 0, stream>>>(outm, ws);
  scl_main<<<2 * TILES, 512, 0, stream>>>(adj, att, outm, ws, out);
  scl_finalize<<<(N + 255) / 256, 256, 0, stream>>>(out, ws);
}